// Round 17
// baseline (30.211 us; speedup 1.0000x reference)
//
#include <hip/hip_runtime.h>

// Problem constants (fixed by the reference)
#define S_N 32
#define O_N 64
#define A_N 8
#define R_N 8
#define B_N 1024
#define T_N 128

// LDS emission block offsets (floats): OT[o][s] | RA[r*8+a][s] | RT[r][s] | PI[s]
#define L_OT 0
#define L_RA 2048
#define L_RT 4096
#define L_PI 4352
#define L_N  4384

typedef float f32x4 __attribute__((ext_vector_type(4)));
typedef short bf16x8 __attribute__((ext_vector_type(8)));

#define RLI(v, l) __builtin_amdgcn_readlane((v), (l))

// v_cvt_pk_bf16_f32: dst = (bf16(lo) in low16, bf16(hi) in high16) — T12 recipe
static __device__ __forceinline__ int cvtpk(float lo, float hi) {
    int r;
    asm("v_cvt_pk_bf16_f32 %0, %1, %2" : "=v"(r) : "v"(lo), "v"(hi));
    return r;
}

union U8 { int i[4]; bf16x8 v; };

// E1 factors for this lane's state pair (h0, h0+16); low 16 bits of PKW.
#define LOADE1(ELO, EHI, PKW) {                                              \
    const unsigned pk_ = (PKW);                                              \
    const int ob_ = L_OT + (int)(pk_ & 63u) * 32 + h0;                       \
    const int rb_ = eBase + (int)((pk_ >> 6) & 7u) * eMulR                   \
                  + (int)((pk_ >> 9) & 7u) * eMulA + h0;                     \
    ELO = sE[ob_] * sE[rb_];                                                 \
    EHI = sE[ob_ + 16] * sE[rb_ + 16]; }

// Build B'-frags for a step pair: P = T_a1 · diag(E2) · T_a2 via 4 MFMAs,
// entirely OFF the u-chain. bp = T2-B-frag (f32) scaled by per-lane E2 vector;
// A-side = T1 rows table (bf16, pre-permuted cols). Product tiles' C/D layout
// interleave-aligns with the u-MFMA B-frag: B.dword[m] = cvtpk(Dlo[m], Dhi[m]).
#define BUILDP(PKW, B0, B1) {                                                \
    const unsigned pk_ = (PKW);                                              \
    const int a1_ = (int)((pk_ >> 9) & 7u);                                  \
    const int o2_ = (int)((pk_ >> 16) & 63u);                                \
    const int a2_ = (int)((pk_ >> 25) & 7u);                                 \
    const int eb2_ = eBase + (int)((pk_ >> 22) & 7u) * eMulR + a2_ * eMulA;  \
    const float4 otl_ = *reinterpret_cast<const float4*>(sE + L_OT + o2_*32 + 4*g); \
    const float4 oth_ = *reinterpret_cast<const float4*>(sE + L_OT + o2_*32 + 4*g + 16); \
    const float4 ral_ = *reinterpret_cast<const float4*>(sE + eb2_ + 4*g);   \
    const float4 rah_ = *reinterpret_cast<const float4*>(sE + eb2_ + 4*g + 16); \
    const bf16x8* pta_ = reinterpret_cast<const bf16x8*>(sTA) + a1_*128 + lane; \
    const bf16x8 ta0_ = pta_[0], ta1_ = pta_[64];                            \
    const float4* ptb_ = reinterpret_cast<const float4*>(sTB) + (a2_*128 + lane)*2; \
    const float4 b0a_ = ptb_[0], b0b_ = ptb_[1];                             \
    const float4 b1a_ = ptb_[128], b1b_ = ptb_[129];                         \
    const float e20_ = otl_.x*ral_.x, e21_ = oth_.x*rah_.x;                  \
    const float e22_ = otl_.y*ral_.y, e23_ = oth_.y*rah_.y;                  \
    const float e24_ = otl_.z*ral_.z, e25_ = oth_.z*rah_.z;                  \
    const float e26_ = otl_.w*ral_.w, e27_ = oth_.w*rah_.w;                  \
    U8 bp0_, bp1_;                                                           \
    bp0_.i[0] = cvtpk(b0a_.x*e20_, b0a_.y*e21_);                             \
    bp0_.i[1] = cvtpk(b0a_.z*e22_, b0a_.w*e23_);                             \
    bp0_.i[2] = cvtpk(b0b_.x*e24_, b0b_.y*e25_);                             \
    bp0_.i[3] = cvtpk(b0b_.z*e26_, b0b_.w*e27_);                             \
    bp1_.i[0] = cvtpk(b1a_.x*e20_, b1a_.y*e21_);                             \
    bp1_.i[1] = cvtpk(b1a_.z*e22_, b1a_.w*e23_);                             \
    bp1_.i[2] = cvtpk(b1b_.x*e24_, b1b_.y*e25_);                             \
    bp1_.i[3] = cvtpk(b1b_.z*e26_, b1b_.w*e27_);                             \
    const f32x4 D00_ = __builtin_amdgcn_mfma_f32_16x16x32_bf16(ta0_, bp0_.v, zf4, 0,0,0); \
    const f32x4 D10_ = __builtin_amdgcn_mfma_f32_16x16x32_bf16(ta1_, bp0_.v, zf4, 0,0,0); \
    const f32x4 D01_ = __builtin_amdgcn_mfma_f32_16x16x32_bf16(ta0_, bp1_.v, zf4, 0,0,0); \
    const f32x4 D11_ = __builtin_amdgcn_mfma_f32_16x16x32_bf16(ta1_, bp1_.v, zf4, 0,0,0); \
    (B0).i[0] = cvtpk(D00_[0], D10_[0]); (B0).i[1] = cvtpk(D00_[1], D10_[1]); \
    (B0).i[2] = cvtpk(D00_[2], D10_[2]); (B0).i[3] = cvtpk(D00_[3], D10_[3]); \
    (B1).i[0] = cvtpk(D01_[0], D11_[0]); (B1).i[1] = cvtpk(D01_[1], D11_[1]); \
    (B1).i[2] = cvtpk(D01_[2], D11_[2]); (B1).i[3] = cvtpk(D01_[3], D11_[3]); }

// The u-chain for one PAIR (or one single step): w = u.*E1; pack; 4 bpermute
// for the A-frag; two MFMAs -> next (ulo, uhi). (r16-validated structure.)
#define CHAINSTEP(E1LO, E1HI, BB0, BB1) {                                    \
    const float wlo_ = ulo * (E1LO), whi_ = uhi * (E1HI);                    \
    const int pw_ = cvtpk(wlo_, whi_);                                       \
    U8 Aw_;                                                                  \
    Aw_.i[0] = __builtin_amdgcn_ds_bpermute(bpb,      pw_);                  \
    Aw_.i[1] = __builtin_amdgcn_ds_bpermute(bpb + 4,  pw_);                  \
    Aw_.i[2] = __builtin_amdgcn_ds_bpermute(bpb + 8,  pw_);                  \
    Aw_.i[3] = __builtin_amdgcn_ds_bpermute(bpb + 12, pw_);                  \
    const f32x4 d0_ = __builtin_amdgcn_mfma_f32_16x16x32_bf16(Aw_.v, (BB0).v, zf4, 0,0,0); \
    const f32x4 d1_ = __builtin_amdgcn_mfma_f32_16x16x32_bf16(Aw_.v, (BB1).v, zf4, 0,0,0); \
    ulo = d0_[0]; uhi = d1_[0]; }

__global__ __launch_bounds__(256) void tam_fused(
    const float* __restrict__ regime,
    const int*   __restrict__ obs,
    const int*   __restrict__ rewards,
    const int*   __restrict__ dones_i,   // float32 0/1 read as int bits
    const int*   __restrict__ actions,
    const float* __restrict__ params_s,
    const float* __restrict__ params_s_sa,
    const float* __restrict__ params_o_s,
    const float* __restrict__ params_r_s,
    const float* __restrict__ params_a_s,
    float* __restrict__ out)
{
    // TA: bf16 A-layout, cols pre-permuted by pi:
    //   sTA[((a*2+h)*64 + 16g + rlow)*8 + j] = T[rlow+16h][a][pi(8g+j)]
    // TB: f32 B-layout, rows pre-permuted by pi:
    //   sTB[((a*2+f)*64 + lane)*8 + j] = T[pi(8*(lane>>4)+j)][a][(lane&15)+16f]
    // pi(8g+2m) = 4g+m ; pi(8g+2m+1) = 4g+m+16
    __shared__ __align__(16) unsigned short sTA[8192];   // 16 KB
    __shared__ __align__(16) float sTB[8192];            // 32 KB
    __shared__ __align__(16) float sE[L_N];              // 17.1 KB
    __shared__ float sAT[256];
    const int tid  = threadIdx.x;
    const int lane = tid & 63;
    const int wid  = tid >> 6;
    const int h0   = lane & 15;
    const int g    = lane >> 4;
    const int bpb  = g * 16;             // bpermute byte addr of src lane 4g
    const int b    = blockIdx.x * 4 + wid;
    const f32x4 zf4 = {0.f, 0.f, 0.f, 0.f};

    // ---------- Phase 1: build tables in LDS ----------
    if (tid < 128) {
        #pragma unroll 1
        for (int rr = 0; rr < 2; ++rr) {
            const int idx = 2 * tid + rr;
            const int s = idx >> 3, a = idx & 7;
            const float* row = params_s_sa + (s * A_N + a) * S_N;
            float p[32];
            #pragma unroll
            for (int i = 0; i < 8; ++i) {
                float4 v = reinterpret_cast<const float4*>(row)[i];
                p[4*i]=v.x; p[4*i+1]=v.y; p[4*i+2]=v.z; p[4*i+3]=v.w;
            }
            float mx = p[0];
            #pragma unroll
            for (int i = 1; i < 32; ++i) mx = fmaxf(mx, p[i]);
            float sum = 0.f;
            #pragma unroll
            for (int i = 0; i < 32; ++i) { p[i] = __expf(p[i] - mx); sum += p[i]; }
            const float inv = 1.0f / sum;
            const int h = s >> 4, rlow = s & 15;
            #pragma unroll
            for (int gg = 0; gg < 4; ++gg) {
                #pragma unroll
                for (int j = 0; j < 8; ++j) {
                    const int dst = 4*gg + (j >> 1) + ((j & 1) << 4);
                    const unsigned bits = __float_as_uint(p[dst] * inv) + 0x8000u;
                    sTA[((a*2 + h)*64 + 16*gg + rlow)*8 + j] =
                        (unsigned short)(bits >> 16);
                }
            }
            // TBf scatter: row s -> (g_s, j_s)
            int gs, js;
            if (s < 16) { gs = s >> 2; js = 2 * (s & 3); }
            else        { gs = (s - 16) >> 2; js = 2 * ((s - 16) & 3) + 1; }
            #pragma unroll
            for (int f = 0; f < 2; ++f)
                #pragma unroll
                for (int c = 0; c < 16; ++c)
                    sTB[((a*2 + f)*64 + 16*gs + c)*8 + js] = p[c + 16*f] * inv;
        }
    } else {
        const int e = tid - 128;
        if (e < 32) {
            const int s = e;
            const float* row = params_o_s + s * O_N;
            float p[64];
            #pragma unroll
            for (int i = 0; i < 16; ++i) {
                float4 v = reinterpret_cast<const float4*>(row)[i];
                p[4*i]=v.x; p[4*i+1]=v.y; p[4*i+2]=v.z; p[4*i+3]=v.w;
            }
            float mx = p[0];
            #pragma unroll
            for (int i = 1; i < 64; ++i) mx = fmaxf(mx, p[i]);
            float sum = 0.f;
            #pragma unroll
            for (int i = 0; i < 64; ++i) { p[i] = __expf(p[i] - mx); sum += p[i]; }
            const float inv = 1.0f / sum;
            #pragma unroll
            for (int o = 0; o < 64; ++o) sE[L_OT + o * 32 + s] = p[o] * inv;
        } else if (e < 64) {
            const int s = e - 32;
            const float* row = params_r_s + s * R_N;
            float p[8];
            #pragma unroll
            for (int i = 0; i < 2; ++i) {
                float4 v = reinterpret_cast<const float4*>(row)[i];
                p[4*i]=v.x; p[4*i+1]=v.y; p[4*i+2]=v.z; p[4*i+3]=v.w;
            }
            float mx = p[0];
            #pragma unroll
            for (int i = 1; i < 8; ++i) mx = fmaxf(mx, p[i]);
            float sum = 0.f;
            #pragma unroll
            for (int i = 0; i < 8; ++i) { p[i] = __expf(p[i] - mx); sum += p[i]; }
            const float inv = 1.0f / sum;
            #pragma unroll
            for (int r = 0; r < 8; ++r) sE[L_RT + r * 32 + s] = p[r] * inv;
        } else if (e < 96) {
            const int s = e - 64;
            const float* row = params_a_s + s * A_N;
            float p[8];
            #pragma unroll
            for (int i = 0; i < 2; ++i) {
                float4 v = reinterpret_cast<const float4*>(row)[i];
                p[4*i]=v.x; p[4*i+1]=v.y; p[4*i+2]=v.z; p[4*i+3]=v.w;
            }
            float mx = p[0];
            #pragma unroll
            for (int i = 1; i < 8; ++i) mx = fmaxf(mx, p[i]);
            float sum = 0.f;
            #pragma unroll
            for (int i = 0; i < 8; ++i) { p[i] = __expf(p[i] - mx); sum += p[i]; }
            const float inv = 1.0f / sum;
            #pragma unroll
            for (int a = 0; a < 8; ++a) sAT[a * 32 + s] = p[a] * inv;
        } else {
            const int s = e - 96;
            float p[32];
            #pragma unroll
            for (int i = 0; i < 8; ++i) {
                float4 v = reinterpret_cast<const float4*>(params_s)[i];
                p[4*i]=v.x; p[4*i+1]=v.y; p[4*i+2]=v.z; p[4*i+3]=v.w;
            }
            float mx = p[0];
            #pragma unroll
            for (int i = 1; i < 32; ++i) mx = fmaxf(mx, p[i]);
            float sum = 0.f;
            #pragma unroll
            for (int i = 0; i < 32; ++i) { p[i] = __expf(p[i] - mx); sum += p[i]; }
            sE[L_PI + s] = p[s] / sum;
        }
    }
    __syncthreads();
    #pragma unroll 1
    for (int i = tid; i < 2048; i += 256) {
        const int sl2 = i & 31, ra = i >> 5;
        sE[L_RA + i] = sE[L_RT + (ra >> 3) * 32 + sl2] * sAT[(ra & 7) * 32 + sl2];
    }
    __syncthreads();

    // ---------- Phase 2: forward filter, 2-step-fused chain ----------
    const int t0 = 2 * lane, t1 = 2 * lane + 1;
    const int o0 = obs[t0 * B_N + b],      o1 = obs[t1 * B_N + b];
    const int r0 = rewards[t0 * B_N + b],  r1 = rewards[t1 * B_N + b];
    const int a0 = actions[t0 * B_N + b],  a1 = actions[t1 * B_N + b];
    const int d0i = dones_i[t0 * B_N + b], d1i = dones_i[t1 * B_N + b];
    const int vpk = (o0 | (r0 << 6) | (a0 << 9)) |
                    ((o1 | (r1 << 6) | (a1 << 9)) << 16);

    const unsigned long long mEv = __ballot(d0i != 0);
    const unsigned long long mOd = __ballot(d1i != 0);
    const int tE = mEv ? 2 * __builtin_ctzll(mEv)     : (1 << 30);
    const int tO = mOd ? 2 * __builtin_ctzll(mOd) + 1 : (1 << 30);
    const int tstar  = tE < tO ? tE : tO;
    const int nsteps = tstar < 128 ? tstar : 128;

    const bool skipA = (regime[b] == 1.0f);
    const int eBase = skipA ? L_RT : L_RA;
    const int eMulR = skipA ? 32 : 256;
    const int eMulA = skipA ? 0 : 32;

    float ulo = sE[L_PI + h0];
    float uhi = sE[L_PI + h0 + 16];
    int ksum = 0;
    float scp = 1.0f;

    U8 B0c, B1c, B0n, B1n;
    float e1clo, e1chi, e1nlo, e1nhi;

    unsigned pkc = (unsigned)RLI(vpk, 0);
    unsigned pkn = (unsigned)RLI(vpk, 1);
    LOADE1(e1clo, e1chi, pkc);
    BUILDP(pkc, B0c, B1c);

    const int npairs = nsteps >> 1;
    #pragma unroll 1
    for (int i = 0; i < npairs; ++i) {
        // off-chain: prefetch + build pair i+1 (P-product on the matrix pipe)
        LOADE1(e1nlo, e1nhi, pkn);
        BUILDP(pkn, B0n, B1n);
        // on-chain: advance 2 steps with ONE redistribution+MFMA pass
        CHAINSTEP(e1clo, e1chi, B0c, B1c);
        // rescale bookkeeping, folded into next pair's E1 (off-chain)
        const int kb = (RLI(__float_as_int(ulo), 0) >> 23) & 255;
        scp = __int_as_float((254 - kb) << 23);
        ksum += kb - 127;
        e1nlo *= scp; e1nhi *= scp;
        // rotate
        B0c = B0n; B1c = B1n; e1clo = e1nlo; e1chi = e1nhi;
        pkc = pkn;
        pkn = (unsigned)RLI(vpk, i + 2);
    }

    if (nsteps & 1) {
        // single leftover step: B-frags straight from TBf (E folded via w);
        // pending scale already folded into e1c by the last loop iteration.
        const int a1s = (int)((pkc >> 9) & 7u);
        const float4* ptb = reinterpret_cast<const float4*>(sTB) + (a1s*128 + lane)*2;
        const float4 s0a = ptb[0], s0b = ptb[1];
        const float4 s1a = ptb[128], s1b = ptb[129];
        U8 Bs0, Bs1;
        Bs0.i[0] = cvtpk(s0a.x, s0a.y); Bs0.i[1] = cvtpk(s0a.z, s0a.w);
        Bs0.i[2] = cvtpk(s0b.x, s0b.y); Bs0.i[3] = cvtpk(s0b.z, s0b.w);
        Bs1.i[0] = cvtpk(s1a.x, s1a.y); Bs1.i[1] = cvtpk(s1a.z, s1a.w);
        Bs1.i[2] = cvtpk(s1b.x, s1b.y); Bs1.i[3] = cvtpk(s1b.z, s1b.w);
        CHAINSTEP(e1clo, e1chi, Bs0, Bs1);
    } else {
        // apply the pending scale that was folded into the (unused) next E1
        ulo *= scp; uhi *= scp;
    }

    // terminal contribution at e = min(t*, 128): OT*RT only (no action term)
    {
        const int e  = nsteps;
        const int oe = obs[e * B_N + b];
        const int re = rewards[e * B_N + b];
        const int ob = L_OT + oe * 32 + h0;
        const int rb = L_RT + re * 32 + h0;
        float t = ulo * sE[ob] * sE[rb] + uhi * sE[ob + 16] * sE[rb + 16];
        t += __shfl_xor(t, 1, 16);
        t += __shfl_xor(t, 2, 16);
        t += __shfl_xor(t, 4, 16);
        t += __shfl_xor(t, 8, 16);
        const float result = (float)ksum * 0.69314718055994531f + __logf(t);
        if (lane == 0) out[b] = result;
    }
}

extern "C" void kernel_launch(void* const* d_in, const int* in_sizes, int n_in,
                              void* d_out, int out_size, void* d_ws, size_t ws_size,
                              hipStream_t stream) {
    (void)in_sizes; (void)n_in; (void)out_size; (void)d_ws; (void)ws_size;
    const float* regime      = (const float*)d_in[0];
    const int*   obs         = (const int*)d_in[1];
    const int*   rewards     = (const int*)d_in[2];
    const int*   dones_i     = (const int*)d_in[3];
    const int*   actions     = (const int*)d_in[4];
    const float* params_s    = (const float*)d_in[5];
    const float* params_s_sa = (const float*)d_in[6];
    const float* params_o_s  = (const float*)d_in[7];
    const float* params_r_s  = (const float*)d_in[8];
    const float* params_a_s  = (const float*)d_in[9];
    float* out = (float*)d_out;

    tam_fused<<<256, 256, 0, stream>>>(regime, obs, rewards, dones_i, actions,
                                       params_s, params_s_sa, params_o_s,
                                       params_r_s, params_a_s, out);
}